// Round 11
// baseline (317.485 us; speedup 1.0000x reference)
//
#include <hip/hip_runtime.h>

// ---------------------------------------------------------------------------
// Causal MHA forward: T=2048, B=2, E=1024, H=16, Dh=64.
// Round 11:
//  - gemm_qkv/gemm_out: REGISTER-PREFETCH pipeline. global_load -> VGPR for
//    tile kk+1 issued before compute(kk); ds_write after barrier. Dependencies
//    run through VGPRs so the compiler's s_waitcnt lands at the ds_write (one
//    full compute phase after issue) instead of vmcnt(0)-draining at the
//    barrier (which defeats global_load_lds dbuf -- R8 lesson / m99 plateau).
//  - XCD swizzles, BK=64, 8-chunk XOR LDS swizzle kept from R10.
//  - attn (R10): register-P, gl2lds dbuf, long-tiles-first, XCD-local bh.
// ---------------------------------------------------------------------------

typedef __attribute__((ext_vector_type(8))) short   s16x8;
typedef __attribute__((ext_vector_type(4))) float   f32x4;
typedef __attribute__((ext_vector_type(2))) __fp16  f16x2;
typedef __attribute__((ext_vector_type(4))) __fp16  f16x4;

#define MFMA16(a, b, c) __builtin_amdgcn_mfma_f32_16x16x32_bf16((a), (b), (c), 0, 0, 0)
#define MFMApv(a, b, c) __builtin_amdgcn_mfma_f32_16x16x16f16((a), (b), (c), 0, 0, 0)

static __device__ __forceinline__ unsigned short f2bf(float f) {
    unsigned u = __float_as_uint(f);
    unsigned r = u + 0x7fffu + ((u >> 16) & 1u);   // RNE
    return (unsigned short)(r >> 16);
}

static __device__ __forceinline__ void gl2lds16(const void* g, void* l) {
    __builtin_amdgcn_global_load_lds(
        (const __attribute__((address_space(1))) unsigned int*)g,
        (__attribute__((address_space(3))) unsigned int*)l, 16, 0, 0);
}

// ---------------------------------------------------------------------------
// Fused conversions. Blocks 0..4095: X row bx (=t*2+b) -> bt-major row.
// Blocks 4096..8191: weights Wq|Wk|Wv|Wo -> Wcat.
__global__ __launch_bounds__(256) void cvt_all(const float* __restrict__ query,
                                               const float* __restrict__ w0,
                                               const float* __restrict__ w1,
                                               const float* __restrict__ w2,
                                               const float* __restrict__ w3,
                                               unsigned short* __restrict__ Xb,
                                               unsigned short* __restrict__ Wcat) {
    const int bx = blockIdx.x;
    if (bx < 4096) {
        const int i = threadIdx.x;                      // float4 within row
        const float4 f = reinterpret_cast<const float4*>(query + (size_t)bx * 1024)[i];
        ushort4 u;
        u.x = f2bf(f.x); u.y = f2bf(f.y); u.z = f2bf(f.z); u.w = f2bf(f.w);
        const int mrow = (bx & 1) * 2048 + (bx >> 1);   // b*2048 + t
        reinterpret_cast<ushort4*>(Xb + (size_t)mrow * 1024)[i] = u;
    } else {
        const int j   = bx - 4096;
        const int sel = j >> 10;
        const int i   = (j & 1023) * 256 + threadIdx.x;
        const float* src = (sel == 0) ? w0 : (sel == 1) ? w1 : (sel == 2) ? w2 : w3;
        const float4 f = reinterpret_cast<const float4*>(src)[i];
        ushort4 u;
        u.x = f2bf(f.x); u.y = f2bf(f.y); u.z = f2bf(f.z); u.w = f2bf(f.w);
        reinterpret_cast<ushort4*>(Wcat + (size_t)sel * 1048576)[i] = u;
    }
}

// ---------------------------------------------------------------------------
// QKV GEMM: C[m,n] = sum_k A[m,k]*W[n,k] + bias. 128x128 tile, BK=64,
// register-prefetch staging, 8-chunk XOR LDS swizzle, b128 fragments.
// 1D grid 768, XCD swizzle. n<2048 -> QKb bf16 (Q scaled 0.125*log2e);
// n>=2048 -> Vt[bh][d][t] fp16 via LDS transpose.
__global__ __launch_bounds__(256) void gemm_qkv(const unsigned short* __restrict__ A,
                                                const unsigned short* __restrict__ W,
                                                const float* __restrict__ b0,
                                                const float* __restrict__ b1,
                                                const float* __restrict__ b2,
                                                unsigned short* __restrict__ outQK,
                                                __fp16* __restrict__ outV) {
    __shared__ __align__(16) unsigned short smem[16384];   // 32 KB
    unsigned short* Al = smem;                              // [128][64]
    unsigned short* Bl = smem + 8192;                       // [128][64]

    const int tid  = threadIdx.x;
    const int w    = tid >> 6;
    const int lane = tid & 63;
    const int quad = lane >> 4;
    const int c    = lane & 15;
    const int wm   = w >> 1;
    const int wn   = w & 1;

    const int id   = blockIdx.x;             // 0..767
    const int xcd  = id & 7;
    const int slot = id >> 3;                // 0..95
    const int m0 = (xcd * 4 + (slot & 3)) * 128;
    const int n0 = (slot >> 2) * 128;

    f32x4 acc[4][4];
    #pragma unroll
    for (int mi = 0; mi < 4; ++mi)
        #pragma unroll
        for (int ni = 0; ni < 4; ++ni) acc[mi][ni] = (f32x4){0.f, 0.f, 0.f, 0.f};

    // staging map: phys LDS slot (tid&7) of row (tid>>3)+32i holds global
    // chunk (tid&7)^(row&7); row&7 invariant under +32.
    const int srow = tid >> 3;               // 0..31
    const int g    = (tid & 7) ^ (srow & 7);
    const unsigned short* aG = A + (size_t)(m0 + srow) * 1024 + g * 8;
    const unsigned short* wG = W + (size_t)(n0 + srow) * 1024 + g * 8;
    const int loff = tid * 8;                // shorts

    const int cs = (c & 7);                  // read-side deswizzle key

    uint4 ra[4], rb[4];
    // prologue: tile 0 -> regs -> LDS
    #pragma unroll
    for (int i = 0; i < 4; ++i) {
        ra[i] = *reinterpret_cast<const uint4*>(aG + i * 32 * 1024);
        rb[i] = *reinterpret_cast<const uint4*>(wG + i * 32 * 1024);
    }
    #pragma unroll
    for (int i = 0; i < 4; ++i) {
        *reinterpret_cast<uint4*>(&Al[loff + i * 2048]) = ra[i];
        *reinterpret_cast<uint4*>(&Bl[loff + i * 2048]) = rb[i];
    }
    __syncthreads();

    for (int kk = 0; kk < 16; ++kk) {
        if (kk + 1 < 16) {
            const int k1 = (kk + 1) * 64;
            #pragma unroll
            for (int i = 0; i < 4; ++i) {
                ra[i] = *reinterpret_cast<const uint4*>(aG + k1 + i * 32 * 1024);
                rb[i] = *reinterpret_cast<const uint4*>(wG + k1 + i * 32 * 1024);
            }
        }

        s16x8 af[4][2], bf[4][2];
        #pragma unroll
        for (int mi = 0; mi < 4; ++mi) {
            const int row = (wm * 64 + mi * 16 + c) * 64;
            af[mi][0] = *reinterpret_cast<const s16x8*>(&Al[row + ((quad ^ cs) << 3)]);
            af[mi][1] = *reinterpret_cast<const s16x8*>(&Al[row + (((4 + quad) ^ cs) << 3)]);
        }
        #pragma unroll
        for (int ni = 0; ni < 4; ++ni) {
            const int row = (wn * 64 + ni * 16 + c) * 64;
            bf[ni][0] = *reinterpret_cast<const s16x8*>(&Bl[row + ((quad ^ cs) << 3)]);
            bf[ni][1] = *reinterpret_cast<const s16x8*>(&Bl[row + (((4 + quad) ^ cs) << 3)]);
        }
        #pragma unroll
        for (int mi = 0; mi < 4; ++mi)
            #pragma unroll
            for (int ni = 0; ni < 4; ++ni) {
                acc[mi][ni] = MFMA16(af[mi][0], bf[ni][0], acc[mi][ni]);
                acc[mi][ni] = MFMA16(af[mi][1], bf[ni][1], acc[mi][ni]);
            }

        __syncthreads();                     // all waves done reading LDS
        if (kk + 1 < 16) {
            #pragma unroll
            for (int i = 0; i < 4; ++i) {    // vmcnt wait lands HERE (hidden)
                *reinterpret_cast<uint4*>(&Al[loff + i * 2048]) = ra[i];
                *reinterpret_cast<uint4*>(&Bl[loff + i * 2048]) = rb[i];
            }
        }
        __syncthreads();                     // writes visible
    }

    const int sel = n0 >> 10;                // uniform per block
    if (sel < 2) {
        const float scale = (sel == 0) ? 0.18033688011112042f : 1.0f; // 0.125*log2e
        const float* bias = (sel == 0) ? b0 : b1;
        #pragma unroll
        for (int ni = 0; ni < 4; ++ni) {
            const int n = n0 + wn * 64 + ni * 16 + c;
            const float bval = bias[n & 1023];
            #pragma unroll
            for (int mi = 0; mi < 4; ++mi)
                #pragma unroll
                for (int r = 0; r < 4; ++r) {
                    const int m = m0 + wm * 64 + mi * 16 + quad * 4 + r;
                    outQK[(size_t)m * 2048 + n] = f2bf((acc[mi][ni][r] + bval) * scale);
                }
        }
    } else {
        // V: transpose through LDS (32 KB tile [128 n][128 m] fp16, 16B-chunk
        // XOR swizzle), then 16B-contiguous stores of t.
        #pragma unroll
        for (int ni = 0; ni < 4; ++ni) {
            const int n = wn * 64 + ni * 16 + c;            // local col (d-dir)
            const float bval = b2[(n0 - 2048) + n];
            #pragma unroll
            for (int mi = 0; mi < 4; ++mi) {
                const int m = wm * 64 + mi * 16 + quad * 4; // local row (t-dir)
                const f16x2 lo = __builtin_amdgcn_cvt_pkrtz(acc[mi][ni][0] + bval,
                                                            acc[mi][ni][1] + bval);
                const f16x2 hi = __builtin_amdgcn_cvt_pkrtz(acc[mi][ni][2] + bval,
                                                            acc[mi][ni][3] + bval);
                uint2 st;
                st.x = __builtin_bit_cast(unsigned int, lo);
                st.y = __builtin_bit_cast(unsigned int, hi);
                const int phys = n * 128 + (((m >> 3) ^ (n & 15)) << 3) + (m & 7);
                *reinterpret_cast<uint2*>(&smem[phys]) = st;
            }
        }
        __syncthreads();
        const int n = tid >> 1;
        const int vcol = (n0 - 2048) + n;
        const int bb = m0 >> 11, tbase = m0 & 2047;
        __fp16* vdst = outV + ((size_t)((bb * 16 + (vcol >> 6)) * 64 + (vcol & 63))) * 2048 + tbase;
        #pragma unroll
        for (int j = 0; j < 8; ++j) {
            const int lc = (tid & 1) * 8 + j;
            const int phys = n * 128 + ((lc ^ (n & 15)) << 3);
            *reinterpret_cast<uint4*>(vdst + lc * 8) =
                *reinterpret_cast<const uint4*>(&smem[phys]);
        }
    }
}

// ---------------------------------------------------------------------------
// Output projection: out[2t+b][n] = sum_k attn[m][k]*Wo[n][k] + bo[n].
// 64x128 tile, BK=64, register-prefetch staging. 1D grid 512, XCD swizzle.
__global__ __launch_bounds__(256) void gemm_out(const unsigned short* __restrict__ A,
                                                const unsigned short* __restrict__ W,
                                                const float* __restrict__ bias,
                                                float* __restrict__ outF) {
    __shared__ __align__(16) unsigned short Al[64 * 64];    // 8 KB
    __shared__ __align__(16) unsigned short Bl[128 * 64];   // 16 KB

    const int tid  = threadIdx.x;
    const int w    = tid >> 6;
    const int lane = tid & 63;
    const int quad = lane >> 4;
    const int c    = lane & 15;

    const int id   = blockIdx.x;             // 0..511
    const int xcd  = id & 7;
    const int slot = id >> 3;                // 0..63
    const int m0 = (xcd * 8 + (slot & 7)) * 64;
    const int n0 = (slot >> 3) * 128;

    f32x4 acc[8];
    #pragma unroll
    for (int ni = 0; ni < 8; ++ni) acc[ni] = (f32x4){0.f, 0.f, 0.f, 0.f};

    const int srow = tid >> 3;
    const int g    = (tid & 7) ^ (srow & 7);
    const unsigned short* aG = A + (size_t)(m0 + srow) * 1024 + g * 8;
    const unsigned short* wG = W + (size_t)(n0 + srow) * 1024 + g * 8;
    const int loff = tid * 8;

    const int cs = (c & 7);

    uint4 ra[2], rb[4];
    #pragma unroll
    for (int i = 0; i < 2; ++i)
        ra[i] = *reinterpret_cast<const uint4*>(aG + i * 32 * 1024);
    #pragma unroll
    for (int i = 0; i < 4; ++i)
        rb[i] = *reinterpret_cast<const uint4*>(wG + i * 32 * 1024);
    #pragma unroll
    for (int i = 0; i < 2; ++i)
        *reinterpret_cast<uint4*>(&Al[loff + i * 2048]) = ra[i];
    #pragma unroll
    for (int i = 0; i < 4; ++i)
        *reinterpret_cast<uint4*>(&Bl[loff + i * 2048]) = rb[i];
    __syncthreads();

    for (int kk = 0; kk < 16; ++kk) {
        if (kk + 1 < 16) {
            const int k1 = (kk + 1) * 64;
            #pragma unroll
            for (int i = 0; i < 2; ++i)
                ra[i] = *reinterpret_cast<const uint4*>(aG + k1 + i * 32 * 1024);
            #pragma unroll
            for (int i = 0; i < 4; ++i)
                rb[i] = *reinterpret_cast<const uint4*>(wG + k1 + i * 32 * 1024);
        }

        const int arow = (w * 16 + c) * 64;
        const s16x8 af0 = *reinterpret_cast<const s16x8*>(&Al[arow + ((quad ^ cs) << 3)]);
        const s16x8 af1 = *reinterpret_cast<const s16x8*>(&Al[arow + (((4 + quad) ^ cs) << 3)]);
        #pragma unroll
        for (int ni = 0; ni < 8; ++ni) {
            const int brow = (ni * 16 + c) * 64;
            const s16x8 bf0 = *reinterpret_cast<const s16x8*>(&Bl[brow + ((quad ^ cs) << 3)]);
            const s16x8 bf1 = *reinterpret_cast<const s16x8*>(&Bl[brow + (((4 + quad) ^ cs) << 3)]);
            acc[ni] = MFMA16(af0, bf0, acc[ni]);
            acc[ni] = MFMA16(af1, bf1, acc[ni]);
        }

        __syncthreads();
        if (kk + 1 < 16) {
            #pragma unroll
            for (int i = 0; i < 2; ++i)
                *reinterpret_cast<uint4*>(&Al[loff + i * 2048]) = ra[i];
            #pragma unroll
            for (int i = 0; i < 4; ++i)
                *reinterpret_cast<uint4*>(&Bl[loff + i * 2048]) = rb[i];
        }
        __syncthreads();
    }

    #pragma unroll
    for (int ni = 0; ni < 8; ++ni) {
        const int n = n0 + ni * 16 + c;
        const float bval = bias[n];
        const int m = m0 + w * 16 + quad * 4;
        const int bb = m >> 11, t = m & 2047;
        #pragma unroll
        for (int r = 0; r < 4; ++r)
            outF[(size_t)(2 * (t + r) + bb) * 1024 + n] = acc[ni][r] + bval;
    }
}

// ---------------------------------------------------------------------------
// Causal attention, register-resident P, single-barrier double-buffered K/V.
// 1D grid 1024, XCD swizzle: xcd owns bh 4*xcd..4*xcd+3; q-tiles long-first.
__global__ __launch_bounds__(256, 4) void attn_kernel(const unsigned short* __restrict__ QKb,
                                                      const __fp16* __restrict__ Vt,
                                                      unsigned short* __restrict__ Ob) {
    __shared__ unsigned short Kl[2][2][64][32];  // [buf][e-half][s][32] 16 KB
    __shared__ __fp16 Vl[2][64][64];             // [buf][d][s] swizzled chunks 16 KB

    const int tid  = threadIdx.x;
    const int w    = tid >> 6;
    const int lane = tid & 63;
    const int quad = lane >> 4;
    const int c    = lane & 15;

    const int id = blockIdx.x;                   // 0..1023
    const int bh = (id & 7) * 4 + ((id >> 3) & 3);
    const int a  = 31 - (id >> 5);               // q-tile index, long first
    const int bB = bh >> 4, h = bh & 15;
    const int t0 = a * 64;
    const int trg = t0 + w * 16;
    const int nIt = a + 1;

    // Q fragments (rows bt-major: bB*2048 + t), pre-scaled
    const unsigned short* qp = QKb + (size_t)(bB * 2048 + trg + c) * 2048 + h * 64 + quad * 8;
    const s16x8 aq0 = *reinterpret_cast<const s16x8*>(qp);
    const s16x8 aq1 = *reinterpret_cast<const s16x8*>(qp + 32);

    // K staging: wave w stages s-rows w*16+(lane>>2); chunk (lane&3) holds
    // source chunk (lane&3) ^ ((row>>1)&3).
    const int lr4 = lane >> 2, sl4 = lane & 3;
    const unsigned short* kSrc = QKb + (size_t)(bB * 2048 + w * 16 + lr4) * 2048
                                 + 1024 + h * 64 + (sl4 ^ ((lane >> 3) & 3)) * 8;
    // V staging: slot (lane&7) holds source chunk (lane&7) ^ (row&7).
    const int vr8 = lane >> 3, sl8 = lane & 7;
    const __fp16* vSrcA = Vt + (size_t)(bh * 64 + w * 16 + vr8) * 2048 + (sl8 ^ vr8) * 8;
    const __fp16* vSrcB = vSrcA + (size_t)8 * 2048;

    f32x4 acc[4];
    float l = 0.f;
    #pragma unroll
    for (int dt = 0; dt < 4; ++dt) acc[dt] = (f32x4){0.f, 0.f, 0.f, 0.f};

    const int kswz = (quad ^ ((c >> 1) & 3)) * 8;

    // prologue: prefetch tile 0 into buf 0
    {
        gl2lds16(kSrc,      &Kl[0][0][w * 16 + lr4][sl4 * 8]);
        gl2lds16(kSrc + 32, &Kl[0][1][w * 16 + lr4][sl4 * 8]);
        gl2lds16(vSrcA,     &Vl[0][w * 16 + vr8][sl8 * 8]);
        gl2lds16(vSrcB,     &Vl[0][w * 16 + 8 + vr8][sl8 * 8]);
    }

    for (int it = 0; it < nIt; ++it) {
        const int buf = it & 1;
        __syncthreads();            // drains vmcnt -> buf's staging complete+visible
        if (it + 1 < nIt) {
            const size_t s1 = (size_t)(it + 1) * 64;
            const int nb = buf ^ 1;
            gl2lds16(kSrc + s1 * 2048,      &Kl[nb][0][w * 16 + lr4][sl4 * 8]);
            gl2lds16(kSrc + s1 * 2048 + 32, &Kl[nb][1][w * 16 + lr4][sl4 * 8]);
            gl2lds16(vSrcA + s1,            &Vl[nb][w * 16 + vr8][sl8 * 8]);
            gl2lds16(vSrcB + s1,            &Vl[nb][w * 16 + 8 + vr8][sl8 * 8]);
        }

        // K fragments (A-operand of S^T: lane c holds s-row ns*16+c)
        s16x8 kf[4][2];
        #pragma unroll
        for (int ns = 0; ns < 4; ++ns) {
            kf[ns][0] = *reinterpret_cast<const s16x8*>(&Kl[buf][0][ns * 16 + c][kswz]);
            kf[ns][1] = *reinterpret_cast<const s16x8*>(&Kl[buf][1][ns * 16 + c][kswz]);
        }
        // V^T fragments: element [dt*16+c][ch*16+quad*4], chunk-swizzled by (c&7)
        f16x4 vf[4][4];
        #pragma unroll
        for (int dt = 0; dt < 4; ++dt)
            #pragma unroll
            for (int ch = 0; ch < 4; ++ch) {
                const int phys = ((2 * ch + (quad >> 1)) ^ (c & 7)) * 8 + (quad & 1) * 4;
                vf[dt][ch] = *reinterpret_cast<const f16x4*>(&Vl[buf][dt * 16 + c][phys]);
            }

        const int s0 = it * 64;
        const bool diag = (it == a);
        // S^T = K Q^T  (C-layout: lane holds s = ns*16+quad*4+r, q = c)
        f32x4 sT[4];
        #pragma unroll
        for (int ns = 0; ns < 4; ++ns) {
            f32x4 z = (f32x4){0.f, 0.f, 0.f, 0.f};
            z = MFMA16(kf[ns][0], aq0, z);
            sT[ns] = MFMA16(kf[ns][1], aq1, z);
        }
        // exp2, mask, pack to fp16 (B-operand layout of 16x16x16 == C-layout)
        f16x4 pf[4];
        float lp = 0.f;
        #pragma unroll
        for (int ns = 0; ns < 4; ++ns) {
            float pv[4];
            #pragma unroll
            for (int r = 0; r < 4; ++r) pv[r] = exp2f(sT[ns][r]);
            if (diag) {
                const int sb = s0 + ns * 16 + quad * 4;
                const int qg = trg + c;
                #pragma unroll
                for (int r = 0; r < 4; ++r) if (sb + r > qg) pv[r] = 0.f;
            }
            lp += (pv[0] + pv[1]) + (pv[2] + pv[3]);
            const f16x2 lo = __builtin_amdgcn_cvt_pkrtz(pv[0], pv[1]);
            const f16x2 hi = __builtin_amdgcn_cvt_pkrtz(pv[2], pv[3]);
            pf[ns] = __builtin_shufflevector(lo, hi, 0, 1, 2, 3);
        }
        l += lp;
        // O^T += V^T P^T
        #pragma unroll
        for (int dt = 0; dt < 4; ++dt)
            #pragma unroll
            for (int ns = 0; ns < 4; ++ns)
                acc[dt] = MFMApv(vf[dt][ns], pf[ns], acc[dt]);
    }

    // epilogue: l split across quads -> reduce over quads only.
    float lv = l;
    lv += __shfl_xor(lv, 16);
    lv += __shfl_xor(lv, 32);
    const float inv = 1.0f / lv;
    const size_t base = (size_t)(bB * 2048 + trg + c) * 1024 + h * 64;
    #pragma unroll
    for (int dt = 0; dt < 4; ++dt) {
        const unsigned u0 = (unsigned)f2bf(acc[dt][0] * inv)
                          | ((unsigned)f2bf(acc[dt][1] * inv) << 16);
        const unsigned u1 = (unsigned)f2bf(acc[dt][2] * inv)
                          | ((unsigned)f2bf(acc[dt][3] * inv) << 16);
        uint2 st; st.x = u0; st.y = u1;
        *reinterpret_cast<uint2*>(Ob + base + dt * 16 + quad * 4) = st;
    }
}

// ---------------------------------------------------------------------------
extern "C" void kernel_launch(void* const* d_in, const int* in_sizes, int n_in,
                              void* d_out, int out_size, void* d_ws, size_t ws_size,
                              hipStream_t stream) {
    const float* query = (const float*)d_in[0];
    const float* Wq    = (const float*)d_in[1];
    const float* bq    = (const float*)d_in[2];
    const float* Wk    = (const float*)d_in[3];
    const float* bk    = (const float*)d_in[4];
    const float* Wv    = (const float*)d_in[5];
    const float* bv    = (const float*)d_in[6];
    const float* Wo    = (const float*)d_in[7];
    const float* bo    = (const float*)d_in[8];
    // d_in[9] = attn_mask: exactly causal; implemented directly.

    float* out = (float*)d_out;

    unsigned short* ws    = (unsigned short*)d_ws;
    unsigned short* Xbf   = ws;                                  // [4096][1024] bt-major
    unsigned short* Wcat  = Xbf  + (size_t)4096 * 1024;          // Wq|Wk|Wv|Wo
    unsigned short* QKb   = Wcat + (size_t)4 * 1024 * 1024;      // [4096][2048] Q|K
    __fp16*         Vtw   = (__fp16*)(QKb + (size_t)4096 * 2048);// [32][64][2048] fp16
    unsigned short* attnb = (unsigned short*)(Vtw + (size_t)32 * 64 * 2048);

    cvt_all<<<8192, 256, 0, stream>>>(query, Wq, Wk, Wv, Wo, Xbf, Wcat);

    gemm_qkv<<<768, 256, 0, stream>>>(Xbf, Wcat, bq, bk, bv, QKb, Vtw);

    attn_kernel<<<1024, 256, 0, stream>>>(QKb, Vtw, attnb);

    gemm_out<<<512, 256, 0, stream>>>(attnb, Wcat + (size_t)3 * 1024 * 1024,
                                      bo, out);
}

// Round 12
// 200.345 us; speedup vs baseline: 1.5847x; 1.5847x over previous
//
#include <hip/hip_runtime.h>

// ---------------------------------------------------------------------------
// Causal MHA forward: T=2048, B=2, E=1024, H=16, Dh=64.
// Round 12 = R10 baseline restored (R11 register-prefetch spilled to scratch:
// WRITE_SIZE 24->200 MB, 2-4x slower) + gemm_out BK=128 (8 iters, half the
// barrier drains, 32 MFMA/wave/iter, LDS 48 KB, per-ni bf loads to avoid
// register pressure).
// ---------------------------------------------------------------------------

typedef __attribute__((ext_vector_type(8))) short   s16x8;
typedef __attribute__((ext_vector_type(4))) float   f32x4;
typedef __attribute__((ext_vector_type(2))) __fp16  f16x2;
typedef __attribute__((ext_vector_type(4))) __fp16  f16x4;

#define MFMA16(a, b, c) __builtin_amdgcn_mfma_f32_16x16x32_bf16((a), (b), (c), 0, 0, 0)
#define MFMApv(a, b, c) __builtin_amdgcn_mfma_f32_16x16x16f16((a), (b), (c), 0, 0, 0)

static __device__ __forceinline__ unsigned short f2bf(float f) {
    unsigned u = __float_as_uint(f);
    unsigned r = u + 0x7fffu + ((u >> 16) & 1u);   // RNE
    return (unsigned short)(r >> 16);
}

static __device__ __forceinline__ void gl2lds16(const void* g, void* l) {
    __builtin_amdgcn_global_load_lds(
        (const __attribute__((address_space(1))) unsigned int*)g,
        (__attribute__((address_space(3))) unsigned int*)l, 16, 0, 0);
}

// ---------------------------------------------------------------------------
// Fused conversions. Blocks 0..4095: X row bx (=t*2+b) -> bt-major row.
// Blocks 4096..8191: weights Wq|Wk|Wv|Wo -> Wcat.
__global__ __launch_bounds__(256) void cvt_all(const float* __restrict__ query,
                                               const float* __restrict__ w0,
                                               const float* __restrict__ w1,
                                               const float* __restrict__ w2,
                                               const float* __restrict__ w3,
                                               unsigned short* __restrict__ Xb,
                                               unsigned short* __restrict__ Wcat) {
    const int bx = blockIdx.x;
    if (bx < 4096) {
        const int i = threadIdx.x;                      // float4 within row
        const float4 f = reinterpret_cast<const float4*>(query + (size_t)bx * 1024)[i];
        ushort4 u;
        u.x = f2bf(f.x); u.y = f2bf(f.y); u.z = f2bf(f.z); u.w = f2bf(f.w);
        const int mrow = (bx & 1) * 2048 + (bx >> 1);   // b*2048 + t
        reinterpret_cast<ushort4*>(Xb + (size_t)mrow * 1024)[i] = u;
    } else {
        const int j   = bx - 4096;
        const int sel = j >> 10;
        const int i   = (j & 1023) * 256 + threadIdx.x;
        const float* src = (sel == 0) ? w0 : (sel == 1) ? w1 : (sel == 2) ? w2 : w3;
        const float4 f = reinterpret_cast<const float4*>(src)[i];
        ushort4 u;
        u.x = f2bf(f.x); u.y = f2bf(f.y); u.z = f2bf(f.z); u.w = f2bf(f.w);
        reinterpret_cast<ushort4*>(Wcat + (size_t)sel * 1048576)[i] = u;
    }
}

// ---------------------------------------------------------------------------
// QKV GEMM (R10): 128x128 tile, BK=64, 2-barrier gl2lds staging, 8-chunk XOR
// swizzle, b128 frags. 1D grid 768, XCD swizzle. n<2048 -> QKb bf16 (Q scaled
// 0.125*log2e); n>=2048 -> Vt[bh][d][t] fp16 via LDS transpose.
__global__ __launch_bounds__(256) void gemm_qkv(const unsigned short* __restrict__ A,
                                                const unsigned short* __restrict__ W,
                                                const float* __restrict__ b0,
                                                const float* __restrict__ b1,
                                                const float* __restrict__ b2,
                                                unsigned short* __restrict__ outQK,
                                                __fp16* __restrict__ outV) {
    __shared__ __align__(16) unsigned short smem[16384];   // 32 KB
    unsigned short* Al = smem;                              // [128][64]
    unsigned short* Bl = smem + 8192;                       // [128][64]

    const int tid  = threadIdx.x;
    const int w    = tid >> 6;
    const int lane = tid & 63;
    const int quad = lane >> 4;
    const int c    = lane & 15;
    const int wm   = w >> 1;
    const int wn   = w & 1;

    const int id   = blockIdx.x;             // 0..767
    const int xcd  = id & 7;
    const int slot = id >> 3;                // 0..95
    const int m0 = (xcd * 4 + (slot & 3)) * 128;
    const int n0 = (slot >> 2) * 128;

    f32x4 acc[4][4];
    #pragma unroll
    for (int mi = 0; mi < 4; ++mi)
        #pragma unroll
        for (int ni = 0; ni < 4; ++ni) acc[mi][ni] = (f32x4){0.f, 0.f, 0.f, 0.f};

    const int srow = tid >> 3;               // 0..31
    const int g    = (tid & 7) ^ (srow & 7);
    const unsigned short* aG = A + (size_t)(m0 + srow) * 1024 + g * 8;
    const unsigned short* wG = W + (size_t)(n0 + srow) * 1024 + g * 8;
    const int loff = tid * 8;                // shorts

    const int cs = (c & 7);                  // read-side deswizzle key

    for (int kk = 0; kk < 16; ++kk) {
        const int k0 = kk * 64;
        __syncthreads();
        #pragma unroll
        for (int i = 0; i < 4; ++i) {
            gl2lds16(aG + k0 + i * 32 * 1024, &Al[loff + i * 2048]);
            gl2lds16(wG + k0 + i * 32 * 1024, &Bl[loff + i * 2048]);
        }
        __syncthreads();

        s16x8 af[4][2], bf[4][2];
        #pragma unroll
        for (int mi = 0; mi < 4; ++mi) {
            const int row = (wm * 64 + mi * 16 + c) * 64;
            af[mi][0] = *reinterpret_cast<const s16x8*>(&Al[row + ((quad ^ cs) << 3)]);
            af[mi][1] = *reinterpret_cast<const s16x8*>(&Al[row + (((4 + quad) ^ cs) << 3)]);
        }
        #pragma unroll
        for (int ni = 0; ni < 4; ++ni) {
            const int row = (wn * 64 + ni * 16 + c) * 64;
            bf[ni][0] = *reinterpret_cast<const s16x8*>(&Bl[row + ((quad ^ cs) << 3)]);
            bf[ni][1] = *reinterpret_cast<const s16x8*>(&Bl[row + (((4 + quad) ^ cs) << 3)]);
        }
        #pragma unroll
        for (int mi = 0; mi < 4; ++mi)
            #pragma unroll
            for (int ni = 0; ni < 4; ++ni) {
                acc[mi][ni] = MFMA16(af[mi][0], bf[ni][0], acc[mi][ni]);
                acc[mi][ni] = MFMA16(af[mi][1], bf[ni][1], acc[mi][ni]);
            }
    }

    const int sel = n0 >> 10;                // uniform per block
    if (sel < 2) {
        const float scale = (sel == 0) ? 0.18033688011112042f : 1.0f; // 0.125*log2e
        const float* bias = (sel == 0) ? b0 : b1;
        #pragma unroll
        for (int ni = 0; ni < 4; ++ni) {
            const int n = n0 + wn * 64 + ni * 16 + c;
            const float bval = bias[n & 1023];
            #pragma unroll
            for (int mi = 0; mi < 4; ++mi)
                #pragma unroll
                for (int r = 0; r < 4; ++r) {
                    const int m = m0 + wm * 64 + mi * 16 + quad * 4 + r;
                    outQK[(size_t)m * 2048 + n] = f2bf((acc[mi][ni][r] + bval) * scale);
                }
        }
    } else {
        // V: transpose through LDS (32 KB tile [128 n][128 m] fp16, 16B-chunk
        // XOR swizzle), then 16B-contiguous stores of t.
        __syncthreads();
        #pragma unroll
        for (int ni = 0; ni < 4; ++ni) {
            const int n = wn * 64 + ni * 16 + c;            // local col (d-dir)
            const float bval = b2[(n0 - 2048) + n];
            #pragma unroll
            for (int mi = 0; mi < 4; ++mi) {
                const int m = wm * 64 + mi * 16 + quad * 4; // local row (t-dir)
                const f16x2 lo = __builtin_amdgcn_cvt_pkrtz(acc[mi][ni][0] + bval,
                                                            acc[mi][ni][1] + bval);
                const f16x2 hi = __builtin_amdgcn_cvt_pkrtz(acc[mi][ni][2] + bval,
                                                            acc[mi][ni][3] + bval);
                uint2 st;
                st.x = __builtin_bit_cast(unsigned int, lo);
                st.y = __builtin_bit_cast(unsigned int, hi);
                const int phys = n * 128 + (((m >> 3) ^ (n & 15)) << 3) + (m & 7);
                *reinterpret_cast<uint2*>(&smem[phys]) = st;
            }
        }
        __syncthreads();
        const int n = tid >> 1;
        const int vcol = (n0 - 2048) + n;
        const int bb = m0 >> 11, tbase = m0 & 2047;
        __fp16* vdst = outV + ((size_t)((bb * 16 + (vcol >> 6)) * 64 + (vcol & 63))) * 2048 + tbase;
        #pragma unroll
        for (int j = 0; j < 8; ++j) {
            const int lc = (tid & 1) * 8 + j;
            const int phys = n * 128 + ((lc ^ (n & 15)) << 3);
            *reinterpret_cast<uint4*>(vdst + lc * 8) =
                *reinterpret_cast<const uint4*>(&smem[phys]);
        }
    }
}

// ---------------------------------------------------------------------------
// Output projection: out[2t+b][n] = sum_k attn[m][k]*Wo[n][k] + bo[n].
// 64x128 tile, BK=128 (8 iters -> half the barrier drains of R10), 2-barrier
// gl2lds staging, 8-chunk XOR swizzle. 1D grid 512, XCD swizzle. LDS 48 KB.
// bf fragments loaded per-ni (keeps VGPRs ~100: no spill -- R11 lesson).
__global__ __launch_bounds__(256) void gemm_out(const unsigned short* __restrict__ A,
                                                const unsigned short* __restrict__ W,
                                                const float* __restrict__ bias,
                                                float* __restrict__ outF) {
    __shared__ __align__(16) unsigned short Al[64 * 128];    // 16 KB
    __shared__ __align__(16) unsigned short Bl[128 * 128];   // 32 KB

    const int tid  = threadIdx.x;
    const int w    = tid >> 6;
    const int lane = tid & 63;
    const int quad = lane >> 4;
    const int c    = lane & 15;

    const int id   = blockIdx.x;             // 0..511
    const int xcd  = id & 7;
    const int slot = id >> 3;                // 0..63
    const int m0 = (xcd * 8 + (slot & 7)) * 64;
    const int n0 = (slot >> 3) * 128;

    f32x4 acc[8];
    #pragma unroll
    for (int ni = 0; ni < 8; ++ni) acc[ni] = (f32x4){0.f, 0.f, 0.f, 0.f};

    // staging: rows of 128 elems = 16 chunks; thread tid covers row (tid>>4)
    // (+16 per issue), phys chunk tid&15 holding source chunk
    // (tid&15)^(row&7); row&7 invariant under +16.
    const int srow = tid >> 4;               // 0..15
    const int g    = (tid & 15) ^ (srow & 7);
    const unsigned short* aG = A + (size_t)(m0 + srow) * 1024 + g * 8;
    const unsigned short* wG = W + (size_t)(n0 + srow) * 1024 + g * 8;
    const int loff = tid * 8;                // shorts; +2048 per issue

    const int cs = (c & 7);

    for (int kk = 0; kk < 8; ++kk) {
        const int k0 = kk * 128;
        __syncthreads();
        #pragma unroll
        for (int i = 0; i < 4; ++i)
            gl2lds16(aG + k0 + i * 16 * 1024, &Al[loff + i * 2048]);
        #pragma unroll
        for (int i = 0; i < 8; ++i)
            gl2lds16(wG + k0 + i * 16 * 1024, &Bl[loff + i * 2048]);
        __syncthreads();

        const int arow = (w * 16 + c) * 128;
        s16x8 af[4];
        #pragma unroll
        for (int kh = 0; kh < 4; ++kh) {
            const int chunk = quad + 4 * kh;
            const int ph = (((chunk & 7) ^ cs) << 3) + ((chunk & 8) << 3);
            af[kh] = *reinterpret_cast<const s16x8*>(&Al[arow + ph]);
        }
        #pragma unroll
        for (int ni = 0; ni < 8; ++ni) {
            const int brow = (ni * 16 + c) * 128;
            #pragma unroll
            for (int kh = 0; kh < 4; ++kh) {
                const int chunk = quad + 4 * kh;
                const int ph = (((chunk & 7) ^ cs) << 3) + ((chunk & 8) << 3);
                const s16x8 bf = *reinterpret_cast<const s16x8*>(&Bl[brow + ph]);
                acc[ni] = MFMA16(af[kh], bf, acc[ni]);
            }
        }
    }

    #pragma unroll
    for (int ni = 0; ni < 8; ++ni) {
        const int n = n0 + ni * 16 + c;
        const float bval = bias[n];
        const int m = m0 + w * 16 + quad * 4;
        const int bb = m >> 11, t = m & 2047;
        #pragma unroll
        for (int r = 0; r < 4; ++r)
            outF[(size_t)(2 * (t + r) + bb) * 1024 + n] = acc[ni][r] + bval;
    }
}

// ---------------------------------------------------------------------------
// Causal attention (R10): register-resident P, single-barrier dbuf K/V.
// 1D grid 1024, XCD swizzle: xcd owns bh 4*xcd..4*xcd+3; q-tiles long-first.
__global__ __launch_bounds__(256, 4) void attn_kernel(const unsigned short* __restrict__ QKb,
                                                      const __fp16* __restrict__ Vt,
                                                      unsigned short* __restrict__ Ob) {
    __shared__ unsigned short Kl[2][2][64][32];  // [buf][e-half][s][32] 16 KB
    __shared__ __fp16 Vl[2][64][64];             // [buf][d][s] swizzled chunks 16 KB

    const int tid  = threadIdx.x;
    const int w    = tid >> 6;
    const int lane = tid & 63;
    const int quad = lane >> 4;
    const int c    = lane & 15;

    const int id = blockIdx.x;                   // 0..1023
    const int bh = (id & 7) * 4 + ((id >> 3) & 3);
    const int a  = 31 - (id >> 5);               // q-tile index, long first
    const int bB = bh >> 4, h = bh & 15;
    const int t0 = a * 64;
    const int trg = t0 + w * 16;
    const int nIt = a + 1;

    const unsigned short* qp = QKb + (size_t)(bB * 2048 + trg + c) * 2048 + h * 64 + quad * 8;
    const s16x8 aq0 = *reinterpret_cast<const s16x8*>(qp);
    const s16x8 aq1 = *reinterpret_cast<const s16x8*>(qp + 32);

    const int lr4 = lane >> 2, sl4 = lane & 3;
    const unsigned short* kSrc = QKb + (size_t)(bB * 2048 + w * 16 + lr4) * 2048
                                 + 1024 + h * 64 + (sl4 ^ ((lane >> 3) & 3)) * 8;
    const int vr8 = lane >> 3, sl8 = lane & 7;
    const __fp16* vSrcA = Vt + (size_t)(bh * 64 + w * 16 + vr8) * 2048 + (sl8 ^ vr8) * 8;
    const __fp16* vSrcB = vSrcA + (size_t)8 * 2048;

    f32x4 acc[4];
    float l = 0.f;
    #pragma unroll
    for (int dt = 0; dt < 4; ++dt) acc[dt] = (f32x4){0.f, 0.f, 0.f, 0.f};

    const int kswz = (quad ^ ((c >> 1) & 3)) * 8;

    {
        gl2lds16(kSrc,      &Kl[0][0][w * 16 + lr4][sl4 * 8]);
        gl2lds16(kSrc + 32, &Kl[0][1][w * 16 + lr4][sl4 * 8]);
        gl2lds16(vSrcA,     &Vl[0][w * 16 + vr8][sl8 * 8]);
        gl2lds16(vSrcB,     &Vl[0][w * 16 + 8 + vr8][sl8 * 8]);
    }

    for (int it = 0; it < nIt; ++it) {
        const int buf = it & 1;
        __syncthreads();            // drains vmcnt -> buf's staging complete+visible
        if (it + 1 < nIt) {
            const size_t s1 = (size_t)(it + 1) * 64;
            const int nb = buf ^ 1;
            gl2lds16(kSrc + s1 * 2048,      &Kl[nb][0][w * 16 + lr4][sl4 * 8]);
            gl2lds16(kSrc + s1 * 2048 + 32, &Kl[nb][1][w * 16 + lr4][sl4 * 8]);
            gl2lds16(vSrcA + s1,            &Vl[nb][w * 16 + vr8][sl8 * 8]);
            gl2lds16(vSrcB + s1,            &Vl[nb][w * 16 + 8 + vr8][sl8 * 8]);
        }

        s16x8 kf[4][2];
        #pragma unroll
        for (int ns = 0; ns < 4; ++ns) {
            kf[ns][0] = *reinterpret_cast<const s16x8*>(&Kl[buf][0][ns * 16 + c][kswz]);
            kf[ns][1] = *reinterpret_cast<const s16x8*>(&Kl[buf][1][ns * 16 + c][kswz]);
        }
        f16x4 vf[4][4];
        #pragma unroll
        for (int dt = 0; dt < 4; ++dt)
            #pragma unroll
            for (int ch = 0; ch < 4; ++ch) {
                const int phys = ((2 * ch + (quad >> 1)) ^ (c & 7)) * 8 + (quad & 1) * 4;
                vf[dt][ch] = *reinterpret_cast<const f16x4*>(&Vl[buf][dt * 16 + c][phys]);
            }

        const int s0 = it * 64;
        const bool diag = (it == a);
        f32x4 sT[4];
        #pragma unroll
        for (int ns = 0; ns < 4; ++ns) {
            f32x4 z = (f32x4){0.f, 0.f, 0.f, 0.f};
            z = MFMA16(kf[ns][0], aq0, z);
            sT[ns] = MFMA16(kf[ns][1], aq1, z);
        }
        f16x4 pf[4];
        float lp = 0.f;
        #pragma unroll
        for (int ns = 0; ns < 4; ++ns) {
            float pv[4];
            #pragma unroll
            for (int r = 0; r < 4; ++r) pv[r] = exp2f(sT[ns][r]);
            if (diag) {
                const int sb = s0 + ns * 16 + quad * 4;
                const int qg = trg + c;
                #pragma unroll
                for (int r = 0; r < 4; ++r) if (sb + r > qg) pv[r] = 0.f;
            }
            lp += (pv[0] + pv[1]) + (pv[2] + pv[3]);
            const f16x2 lo = __builtin_amdgcn_cvt_pkrtz(pv[0], pv[1]);
            const f16x2 hi = __builtin_amdgcn_cvt_pkrtz(pv[2], pv[3]);
            pf[ns] = __builtin_shufflevector(lo, hi, 0, 1, 2, 3);
        }
        l += lp;
        #pragma unroll
        for (int dt = 0; dt < 4; ++dt)
            #pragma unroll
            for (int ns = 0; ns < 4; ++ns)
                acc[dt] = MFMApv(vf[dt][ns], pf[ns], acc[dt]);
    }

    float lv = l;
    lv += __shfl_xor(lv, 16);
    lv += __shfl_xor(lv, 32);
    const float inv = 1.0f / lv;
    const size_t base = (size_t)(bB * 2048 + trg + c) * 1024 + h * 64;
    #pragma unroll
    for (int dt = 0; dt < 4; ++dt) {
        const unsigned u0 = (unsigned)f2bf(acc[dt][0] * inv)
                          | ((unsigned)f2bf(acc[dt][1] * inv) << 16);
        const unsigned u1 = (unsigned)f2bf(acc[dt][2] * inv)
                          | ((unsigned)f2bf(acc[dt][3] * inv) << 16);
        uint2 st; st.x = u0; st.y = u1;
        *reinterpret_cast<uint2*>(Ob + base + dt * 16 + quad * 4) = st;
    }
}

// ---------------------------------------------------------------------------
extern "C" void kernel_launch(void* const* d_in, const int* in_sizes, int n_in,
                              void* d_out, int out_size, void* d_ws, size_t ws_size,
                              hipStream_t stream) {
    const float* query = (const float*)d_in[0];
    const float* Wq    = (const float*)d_in[1];
    const float* bq    = (const float*)d_in[2];
    const float* Wk    = (const float*)d_in[3];
    const float* bk    = (const float*)d_in[4];
    const float* Wv    = (const float*)d_in[5];
    const float* bv    = (const float*)d_in[6];
    const float* Wo    = (const float*)d_in[7];
    const float* bo    = (const float*)d_in[8];
    // d_in[9] = attn_mask: exactly causal; implemented directly.

    float* out = (float*)d_out;

    unsigned short* ws    = (unsigned short*)d_ws;
    unsigned short* Xbf   = ws;                                  // [4096][1024] bt-major
    unsigned short* Wcat  = Xbf  + (size_t)4096 * 1024;          // Wq|Wk|Wv|Wo
    unsigned short* QKb   = Wcat + (size_t)4 * 1024 * 1024;      // [4096][2048] Q|K
    __fp16*         Vtw   = (__fp16*)(QKb + (size_t)4096 * 2048);// [32][64][2048] fp16
    unsigned short* attnb = (unsigned short*)(Vtw + (size_t)32 * 64 * 2048);

    cvt_all<<<8192, 256, 0, stream>>>(query, Wq, Wk, Wv, Wo, Xbf, Wcat);

    gemm_qkv<<<768, 256, 0, stream>>>(Xbf, Wcat, bq, bk, bv, QKb, Vtw);

    attn_kernel<<<1024, 256, 0, stream>>>(QKb, Vtw, attnb);

    gemm_out<<<512, 256, 0, stream>>>(attnb, Wcat + (size_t)3 * 1024 * 1024,
                                      bo, out);
}